// Round 1
// baseline (768.624 us; speedup 1.0000x reference)
//
#include <hip/hip_runtime.h>

typedef __bf16 bfvec8 __attribute__((ext_vector_type(8)));
typedef float f32x4 __attribute__((ext_vector_type(4)));
typedef unsigned short u16x8 __attribute__((ext_vector_type(8)));

constexpr int C_IN = 128, Wd = 56, HW = 3136, K_OUT = 256;
constexpr int KKTOT = 1152;   // 128 * 9
constexpr int LDSS = 40;      // 32 + 8 pad (keeps 16B alignment for b128)

__device__ inline unsigned short f2bf(float f) {
    union { float f; unsigned u; } v; v.f = f;
    unsigned u = v.u;
    u += 0x7fffu + ((u >> 16) & 1u);   // round-to-nearest-even
    return (unsigned short)(u >> 16);
}

__global__ __launch_bounds__(256) void conv3x3_mfma(
    const float* __restrict__ x, const float* __restrict__ wgt,
    const float* __restrict__ bias, float* __restrict__ out)
{
    __shared__ __align__(16) unsigned short As[128 * LDSS];
    __shared__ __align__(16) unsigned short Bs[128 * LDSS];

    const int tid = threadIdx.x;
    const int bx  = blockIdx.x;
    const int ntile = (bx & 1) * 128;
    const int mtile = (bx >> 1) * 128;

    const int lane_m = tid & 127;
    const int grp    = tid >> 7;          // 0..1 -> which 16-channel half of BK=32

    // ---- A-staging precompute (per-thread constants) ----
    const int m    = mtile + lane_m;
    const int nimg = m / HW;
    const int hw   = m - nimg * HW;
    const int h    = hw / Wd;
    const int w    = hw - h * Wd;
    const float* xb = x + (size_t)nimg * C_IN * HW + hw + (size_t)grp * 16 * HW;

    // ---- B-staging precompute ----
    const float* wb = wgt + (size_t)(ntile + lane_m) * KKTOT + grp * 16 * 9;

    // ---- wave/fragment coordinates ----
    const int wave = tid >> 6;
    const int lane = tid & 63;
    const int wrow = (wave >> 1) * 64;
    const int wcol = (wave & 1) * 64;
    const int r16  = lane & 15;
    const int quad = lane >> 4;

    const f32x4 zero4 = {0.f, 0.f, 0.f, 0.f};
    f32x4 acc[4][4];
    #pragma unroll
    for (int i = 0; i < 4; ++i)
        #pragma unroll
        for (int j = 0; j < 4; ++j)
            acc[i][j] = zero4;

    // K-loop: 9 taps (rs) x 4 channel-chunks of 32
    for (int step = 0; step < 36; ++step) {
        const int rs = step >> 2;
        const int c0 = (step & 3) * 32;
        const int r  = rs / 3;
        const int s  = rs - r * 3;
        const bool ok = ((unsigned)(h + r - 1) < 56u) && ((unsigned)(w + s - 1) < 56u);
        const float* ap = xb + (size_t)c0 * HW + (r - 1) * Wd + (s - 1);
        const float* bp = wb + c0 * 9 + rs;

        float av[16], bv[16];
        #pragma unroll
        for (int j = 0; j < 16; ++j)
            av[j] = ok ? ap[(size_t)j * HW] : 0.f;
        #pragma unroll
        for (int j = 0; j < 16; ++j)
            bv[j] = bp[j * 9];

        u16x8 a0, a1, b0, b1;
        #pragma unroll
        for (int j = 0; j < 8; ++j) {
            a0[j] = f2bf(av[j]);  a1[j] = f2bf(av[j + 8]);
            b0[j] = f2bf(bv[j]);  b1[j] = f2bf(bv[j + 8]);
        }

        __syncthreads();   // previous iteration's frag reads complete
        *(u16x8*)&As[lane_m * LDSS + grp * 16]     = a0;
        *(u16x8*)&As[lane_m * LDSS + grp * 16 + 8] = a1;
        *(u16x8*)&Bs[lane_m * LDSS + grp * 16]     = b0;
        *(u16x8*)&Bs[lane_m * LDSS + grp * 16 + 8] = b1;
        __syncthreads();   // staging visible

        bfvec8 af[4], bfr[4];
        #pragma unroll
        for (int mi = 0; mi < 4; ++mi)
            af[mi] = *(const bfvec8*)&As[(wrow + mi * 16 + r16) * LDSS + quad * 8];
        #pragma unroll
        for (int ni = 0; ni < 4; ++ni)
            bfr[ni] = *(const bfvec8*)&Bs[(wcol + ni * 16 + r16) * LDSS + quad * 8];

        #pragma unroll
        for (int mi = 0; mi < 4; ++mi)
            #pragma unroll
            for (int ni = 0; ni < 4; ++ni)
                acc[mi][ni] = __builtin_amdgcn_mfma_f32_16x16x32_bf16(
                    af[mi], bfr[ni], acc[mi][ni], 0, 0, 0);
    }

    // ---- epilogue: D col = lane&15 -> k, row = quad*4+i -> m ----
    #pragma unroll
    for (int ni = 0; ni < 4; ++ni) {
        const int k  = ntile + wcol + ni * 16 + r16;
        const float bb = bias[k];
        #pragma unroll
        for (int mi = 0; mi < 4; ++mi) {
            #pragma unroll
            for (int i = 0; i < 4; ++i) {
                const int me  = mtile + wrow + mi * 16 + quad * 4 + i;
                const int ne  = me / HW;
                const int hwe = me - ne * HW;
                out[((size_t)ne * K_OUT + k) * HW + hwe] = acc[mi][ni][i] + bb;
            }
        }
    }
}

extern "C" void kernel_launch(void* const* d_in, const int* in_sizes, int n_in,
                              void* d_out, int out_size, void* d_ws, size_t ws_size,
                              hipStream_t stream) {
    const float* x    = (const float*)d_in[0];
    const float* wgt  = (const float*)d_in[1];
    const float* bias = (const float*)d_in[2];
    float* out = (float*)d_out;
    dim3 grid(1568), block(256);
    conv3x3_mfma<<<grid, block, 0, stream>>>(x, wgt, bias, out);
}

// Round 2
// 293.990 us; speedup vs baseline: 2.6145x; 2.6145x over previous
//
#include <hip/hip_runtime.h>

typedef __bf16 bfvec8 __attribute__((ext_vector_type(8)));
typedef float f32x4 __attribute__((ext_vector_type(4)));
typedef unsigned short u16x8 __attribute__((ext_vector_type(8)));
typedef unsigned int u32;

constexpr int C_IN = 128, Wd = 56, Hd = 56, HW = 3136, K_OUT = 256, N_IMG = 32;
constexpr int KKTOT = 1152;      // 128*9
constexpr int WP = 58;           // padded H/W
constexpr size_t XP_ELEMS = (size_t)N_IMG * WP * WP * C_IN;   // 13,776,896
constexpr size_t XP_BYTES = XP_ELEMS * 2;                     // 27,553,792
constexpr size_t WT_ELEMS = (size_t)9 * 4 * 2 * 128 * 32;     // 294,912
constexpr size_t WS_NEED  = XP_BYTES + WT_ELEMS * 2;

__device__ inline unsigned short f2bf(float f) {
    union { float f; unsigned u; } v; v.f = f;
    unsigned u = v.u;
    u += 0x7fffu + ((u >> 16) & 1u);   // round-to-nearest-even
    return (unsigned short)(u >> 16);
}

__device__ inline void gld16(const void* g, void* l) {
    __builtin_amdgcn_global_load_lds(
        (const __attribute__((address_space(1))) u32*)g,
        (__attribute__((address_space(3))) u32*)l, 16, 0, 0);
}

// ---- Pre-pass 1: x NCHW fp32 -> halo-padded NHWC bf16 ---------------------
__global__ __launch_bounds__(256) void xpose(const float* __restrict__ x,
                                             unsigned short* __restrict__ xp) {
    __shared__ unsigned short T[Wd * C_IN];   // [w][c] bf16, 14336 B
    const int nb = blockIdx.x;                // n*56 + h
    const int n = nb / Hd, h = nb - n * Hd;
    const float* src = x + (size_t)n * C_IN * HW + h * Wd;
    #pragma unroll
    for (int k = 0; k < 7; ++k) {
        int idx = threadIdx.x + k * 256;      // float4 index 0..1791
        int c = idx / 14, w4 = idx - c * 14;
        const float4 v = *(const float4*)(src + (size_t)c * HW + w4 * 4);
        T[(w4 * 4 + 0) * C_IN + c] = f2bf(v.x);
        T[(w4 * 4 + 1) * C_IN + c] = f2bf(v.y);
        T[(w4 * 4 + 2) * C_IN + c] = f2bf(v.z);
        T[(w4 * 4 + 3) * C_IN + c] = f2bf(v.w);
    }
    __syncthreads();
    // interior rows (w=0..55) are one contiguous 14336 B region in xp
    unsigned short* dst = xp + ((size_t)(n * WP + h + 1) * WP + 1) * C_IN;
    const u16x8* s8 = (const u16x8*)T;
    u16x8* d8 = (u16x8*)dst;
    #pragma unroll
    for (int k = 0; k < 4; ++k) {
        int idx = threadIdx.x + k * 256;
        if (idx < 896) d8[idx] = s8[idx];
    }
}

// ---- Pre-pass 2: weight OIHW fp32 -> fragment-packed bf16 tiles -----------
// wt linear index o = (((rs*4 + chunk)*2 + ntile)*128 + n)*32 + kk
__global__ __launch_bounds__(256) void wxform(const float* __restrict__ w,
                                              unsigned short* __restrict__ wt) {
    int o = blockIdx.x * 256 + threadIdx.x;
    int kk = o & 31, n = (o >> 5) & 127, nt = (o >> 12) & 1,
        ch = (o >> 13) & 3, rs = o >> 15;
    float v = w[(size_t)(nt * 128 + n) * KKTOT + (ch * 32 + kk) * 9 + rs];
    wt[o] = f2bf(v);
}

// ---- Main GEMM: m97 structure, implicit conv via padded NHWC --------------
__global__ __launch_bounds__(256) void conv_gemm(
    const unsigned short* __restrict__ xp, const unsigned short* __restrict__ wt,
    const float* __restrict__ bias, float* __restrict__ out)
{
    __shared__ __align__(16) unsigned short As[128 * 32];  // 8 KB, rows of 64 B
    __shared__ __align__(16) unsigned short Bs[128 * 32];

    const int tid = threadIdx.x;
    const int bx  = blockIdx.x;
    const int nt  = bx & 1;
    const int mtile = (bx >> 1) * 128;

    // A staging global pointers: two 16B loads/thread cover the 8 KB tile
    const int kk0 = (tid & 3) * 8;
    const unsigned short *gA0, *gA1;
    {
        int mrow = tid >> 2;
        int m = mtile + mrow;
        int ni = m / HW; int hw = m - ni * HW; int h = hw / Wd; int w = hw - h * Wd;
        gA0 = xp + ((size_t)(ni * WP + h + 1) * WP + (w + 1)) * C_IN + kk0;
        m += 64;
        ni = m / HW; hw = m - ni * HW; h = hw / Wd; w = hw - h * Wd;
        gA1 = xp + ((size_t)(ni * WP + h + 1) * WP + (w + 1)) * C_IN + kk0;
    }

    const int wave = tid >> 6, lane = tid & 63;
    const int wrow = (wave >> 1) * 64, wcol = (wave & 1) * 64;
    const int r16 = lane & 15, quad = lane >> 4;

    const f32x4 zero4 = {0.f, 0.f, 0.f, 0.f};
    f32x4 acc[4][4];
    #pragma unroll
    for (int i = 0; i < 4; ++i)
        #pragma unroll
        for (int j = 0; j < 4; ++j)
            acc[i][j] = zero4;

    for (int step = 0; step < 36; ++step) {
        const int rs = step >> 2, ch = step & 3;
        const int dr = rs / 3 - 1, dc = rs % 3 - 1;
        const int aoff = (dr * WP + dc) * C_IN + ch * 32;        // wave-uniform
        const size_t boff = (size_t)(((rs * 4 + ch) * 2 + nt) * 4096) + (size_t)tid * 8;

        __syncthreads();   // prior iteration's frag reads complete
        gld16(gA0 + aoff, (void*)(As + tid * 8));
        gld16(gA1 + aoff, (void*)(As + 2048 + tid * 8));
        gld16(wt + boff,        (void*)(Bs + tid * 8));
        gld16(wt + boff + 2048, (void*)(Bs + 2048 + tid * 8));
        __syncthreads();   // staging visible (vmcnt drained)

        bfvec8 af[4], bf[4];
        #pragma unroll
        for (int mi = 0; mi < 4; ++mi)
            af[mi] = *(const bfvec8*)&As[(wrow + mi * 16 + r16) * 32 + quad * 8];
        #pragma unroll
        for (int ni = 0; ni < 4; ++ni)
            bf[ni] = *(const bfvec8*)&Bs[(wcol + ni * 16 + r16) * 32 + quad * 8];

        #pragma unroll
        for (int mi = 0; mi < 4; ++mi)
            #pragma unroll
            for (int ni = 0; ni < 4; ++ni)
                acc[mi][ni] = __builtin_amdgcn_mfma_f32_16x16x32_bf16(
                    af[mi], bf[ni], acc[mi][ni], 0, 0, 0);
    }

    // epilogue: D col = lane&15 -> k, row = quad*4+i -> m  (verified round 1)
    const int ntile = nt * 128;
    #pragma unroll
    for (int ni = 0; ni < 4; ++ni) {
        const int k = ntile + wcol + ni * 16 + r16;
        const float bb = bias[k];
        #pragma unroll
        for (int mi = 0; mi < 4; ++mi) {
            #pragma unroll
            for (int i = 0; i < 4; ++i) {
                const int me  = mtile + wrow + mi * 16 + quad * 4 + i;
                const int ne  = me / HW;
                const int hwe = me - ne * HW;
                out[((size_t)ne * K_OUT + k) * HW + hwe] = acc[mi][ni][i] + bb;
            }
        }
    }
}

// ---- Fallback (round-1 kernel, used only if ws too small) -----------------
constexpr int LDSS = 40;
__global__ __launch_bounds__(256) void conv3x3_fallback(
    const float* __restrict__ x, const float* __restrict__ wgt,
    const float* __restrict__ bias, float* __restrict__ out)
{
    __shared__ __align__(16) unsigned short As[128 * LDSS];
    __shared__ __align__(16) unsigned short Bs[128 * LDSS];
    const int tid = threadIdx.x;
    const int bx  = blockIdx.x;
    const int ntile = (bx & 1) * 128;
    const int mtile = (bx >> 1) * 128;
    const int lane_m = tid & 127;
    const int grp    = tid >> 7;
    const int m    = mtile + lane_m;
    const int nimg = m / HW;
    const int hw   = m - nimg * HW;
    const int h    = hw / Wd;
    const int w    = hw - h * Wd;
    const float* xb = x + (size_t)nimg * C_IN * HW + hw + (size_t)grp * 16 * HW;
    const float* wb = wgt + (size_t)(ntile + lane_m) * KKTOT + grp * 16 * 9;
    const int wave = tid >> 6, lane = tid & 63;
    const int wrow = (wave >> 1) * 64, wcol = (wave & 1) * 64;
    const int r16 = lane & 15, quad = lane >> 4;
    const f32x4 zero4 = {0.f, 0.f, 0.f, 0.f};
    f32x4 acc[4][4];
    for (int i = 0; i < 4; ++i) for (int j = 0; j < 4; ++j) acc[i][j] = zero4;
    for (int step = 0; step < 36; ++step) {
        const int rs = step >> 2;
        const int c0 = (step & 3) * 32;
        const int r  = rs / 3;
        const int s  = rs - r * 3;
        const bool ok = ((unsigned)(h + r - 1) < 56u) && ((unsigned)(w + s - 1) < 56u);
        const float* ap = xb + (size_t)c0 * HW + (r - 1) * Wd + (s - 1);
        const float* bp = wb + c0 * 9 + rs;
        float av[16], bv[16];
        for (int j = 0; j < 16; ++j) av[j] = ok ? ap[(size_t)j * HW] : 0.f;
        for (int j = 0; j < 16; ++j) bv[j] = bp[j * 9];
        u16x8 a0, a1, b0, b1;
        for (int j = 0; j < 8; ++j) {
            a0[j] = f2bf(av[j]);  a1[j] = f2bf(av[j + 8]);
            b0[j] = f2bf(bv[j]);  b1[j] = f2bf(bv[j + 8]);
        }
        __syncthreads();
        *(u16x8*)&As[lane_m * LDSS + grp * 16]     = a0;
        *(u16x8*)&As[lane_m * LDSS + grp * 16 + 8] = a1;
        *(u16x8*)&Bs[lane_m * LDSS + grp * 16]     = b0;
        *(u16x8*)&Bs[lane_m * LDSS + grp * 16 + 8] = b1;
        __syncthreads();
        bfvec8 af[4], bfr[4];
        for (int mi = 0; mi < 4; ++mi)
            af[mi] = *(const bfvec8*)&As[(wrow + mi * 16 + r16) * LDSS + quad * 8];
        for (int ni = 0; ni < 4; ++ni)
            bfr[ni] = *(const bfvec8*)&Bs[(wcol + ni * 16 + r16) * LDSS + quad * 8];
        for (int mi = 0; mi < 4; ++mi)
            for (int ni = 0; ni < 4; ++ni)
                acc[mi][ni] = __builtin_amdgcn_mfma_f32_16x16x32_bf16(
                    af[mi], bfr[ni], acc[mi][ni], 0, 0, 0);
    }
    for (int ni = 0; ni < 4; ++ni) {
        const int k = ntile + wcol + ni * 16 + r16;
        const float bb = bias[k];
        for (int mi = 0; mi < 4; ++mi)
            for (int i = 0; i < 4; ++i) {
                const int me  = mtile + wrow + mi * 16 + quad * 4 + i;
                const int ne  = me / HW;
                const int hwe = me - ne * HW;
                out[((size_t)ne * K_OUT + k) * HW + hwe] = acc[mi][ni][i] + bb;
            }
    }
}

extern "C" void kernel_launch(void* const* d_in, const int* in_sizes, int n_in,
                              void* d_out, int out_size, void* d_ws, size_t ws_size,
                              hipStream_t stream) {
    const float* x    = (const float*)d_in[0];
    const float* wgt  = (const float*)d_in[1];
    const float* bias = (const float*)d_in[2];
    float* out = (float*)d_out;

    if (ws_size < WS_NEED) {
        conv3x3_fallback<<<dim3(1568), dim3(256), 0, stream>>>(x, wgt, bias, out);
        return;
    }
    unsigned short* xp = (unsigned short*)d_ws;
    unsigned short* wt = (unsigned short*)((char*)d_ws + XP_BYTES);

    hipMemsetAsync(d_ws, 0, XP_BYTES, stream);                       // halo zeros
    xpose<<<dim3(N_IMG * Hd), dim3(256), 0, stream>>>(x, xp);
    wxform<<<dim3((int)(WT_ELEMS / 256)), dim3(256), 0, stream>>>(wgt, wt);
    conv_gemm<<<dim3(1568), dim3(256), 0, stream>>>(xp, wt, bias, out);
}

// Round 3
// 231.021 us; speedup vs baseline: 3.3271x; 1.2726x over previous
//
#include <hip/hip_runtime.h>

typedef __bf16 bfvec8 __attribute__((ext_vector_type(8)));
typedef float f32x4 __attribute__((ext_vector_type(4)));
typedef unsigned short u16x8 __attribute__((ext_vector_type(8)));
typedef unsigned int u32;

constexpr int C_IN = 128, Wd = 56, Hd = 56, HW = 3136, K_OUT = 256, N_IMG = 32;
constexpr int KKTOT = 1152;      // 128*9
constexpr int WP = 58;           // padded H/W
constexpr size_t XP_ELEMS = (size_t)N_IMG * WP * WP * C_IN;   // 13,776,896
constexpr size_t XP_BYTES = XP_ELEMS * 2;                     // 27,553,792
constexpr size_t WT_ELEMS = (size_t)9 * 4 * 2 * 128 * 32;     // 294,912
constexpr size_t WS_NEED  = XP_BYTES + WT_ELEMS * 2;

__device__ inline unsigned short f2bf(float f) {
    union { float f; unsigned u; } v; v.f = f;
    unsigned u = v.u;
    u += 0x7fffu + ((u >> 16) & 1u);   // round-to-nearest-even
    return (unsigned short)(u >> 16);
}

__device__ inline void gld16(const void* g, void* l) {
    __builtin_amdgcn_global_load_lds(
        (const __attribute__((address_space(1))) u32*)g,
        (__attribute__((address_space(3))) u32*)l, 16, 0, 0);
}

// ---- Pre-pass 1: x NCHW fp32 -> halo-padded NHWC bf16 ---------------------
// LDS transpose with XOR swizzle: halfword (w,c) stored at
// T[w*128 + (c ^ (((w>>2)&15)*8))]  -> breaks the w-stride bank collision
// on writes; reads stay vec8-contiguous (swizzle only touches c bits 3..6).
__global__ __launch_bounds__(256) void xpose(const float* __restrict__ x,
                                             unsigned short* __restrict__ xp) {
    __shared__ unsigned short T[Wd * C_IN];   // 14336 B
    const int nb = blockIdx.x;                // n*56 + h
    const int n = nb / Hd, h = nb - n * Hd;
    const float* src = x + (size_t)n * C_IN * HW + h * Wd;
    #pragma unroll
    for (int k = 0; k < 7; ++k) {
        int idx = threadIdx.x + k * 256;      // float4 index 0..1791
        int c = idx / 14, w4 = idx - c * 14;
        const float4 v = *(const float4*)(src + (size_t)c * HW + w4 * 4);
        const int sw = (w4 & 15) * 8;         // (w>>2)&15 == w4 for w4<=13
        T[(w4 * 4 + 0) * C_IN + (c ^ sw)] = f2bf(v.x);
        T[(w4 * 4 + 1) * C_IN + (c ^ sw)] = f2bf(v.y);
        T[(w4 * 4 + 2) * C_IN + (c ^ sw)] = f2bf(v.z);
        T[(w4 * 4 + 3) * C_IN + (c ^ sw)] = f2bf(v.w);
    }
    __syncthreads();
    unsigned short* dst = xp + ((size_t)(n * WP + h + 1) * WP + 1) * C_IN;
    const u16x8* s8 = (const u16x8*)T;
    u16x8* d8 = (u16x8*)dst;
    #pragma unroll
    for (int k = 0; k < 4; ++k) {
        int idx = threadIdx.x + k * 256;
        if (idx < 896) {
            int w = idx >> 4, j8 = idx & 15;
            d8[idx] = s8[w * 16 + (j8 ^ ((w >> 2) & 15))];
        }
    }
}

// ---- Pre-pass 2: weight OIHW fp32 -> packed bf16 tiles --------------------
// wt linear index o = (((rs*4 + chunk)*2 + ntile)*128 + n)*32 + kk
__global__ __launch_bounds__(256) void wxform(const float* __restrict__ w,
                                              unsigned short* __restrict__ wt) {
    int o = blockIdx.x * 256 + threadIdx.x;
    int kk = o & 31, n = (o >> 5) & 127, nt = (o >> 12) & 1,
        ch = (o >> 13) & 3, rs = o >> 15;
    float v = w[(size_t)(nt * 128 + n) * KKTOT + (ch * 32 + kk) * 9 + rs];
    wt[o] = f2bf(v);
}

// ---- Main GEMM: m97 structure + XOR-swizzled LDS tiles --------------------
// LDS 16B-slot (row r, cs) holds k-chunk  cs ^ ((r>>1)&3); implemented by
// per-lane SOURCE address choice in global_load_lds (dest is lane-ordered).
__global__ __launch_bounds__(256) void conv_gemm(
    const unsigned short* __restrict__ xp, const unsigned short* __restrict__ wt,
    const float* __restrict__ bias, float* __restrict__ out)
{
    __shared__ __align__(16) unsigned short As[128 * 32];  // 8 KB
    __shared__ __align__(16) unsigned short Bs[128 * 32];

    const int tid = threadIdx.x;
    const int bx  = blockIdx.x;
    const int nt  = bx & 1;
    const int mtile = (bx >> 1) * 128;

    // swizzled chunk this lane must FETCH so that slot (r, tid&3) holds it
    const int cg8 = ((tid & 3) ^ ((tid >> 3) & 3)) * 8;   // halfword offset

    const unsigned short *gA0, *gA1;
    {
        int mrow = tid >> 2;
        int m = mtile + mrow;
        int ni = m / HW; int hw = m - ni * HW; int h = hw / Wd; int w = hw - h * Wd;
        gA0 = xp + ((size_t)(ni * WP + h + 1) * WP + (w + 1)) * C_IN + cg8;
        m += 64;
        ni = m / HW; hw = m - ni * HW; h = hw / Wd; w = hw - h * Wd;
        gA1 = xp + ((size_t)(ni * WP + h + 1) * WP + (w + 1)) * C_IN + cg8;
    }
    const size_t bbase = (size_t)(tid & 0xFC) * 8 + cg8;   // (n-row)*32 + swz chunk

    const int wave = tid >> 6, lane = tid & 63;
    const int wrow = (wave >> 1) * 64, wcol = (wave & 1) * 64;
    const int r16 = lane & 15, quad = lane >> 4;
    const int qsw = (quad ^ ((r16 >> 1) & 3)) * 8;   // swizzled read offset

    const f32x4 zero4 = {0.f, 0.f, 0.f, 0.f};
    f32x4 acc[4][4];
    #pragma unroll
    for (int i = 0; i < 4; ++i)
        #pragma unroll
        for (int j = 0; j < 4; ++j)
            acc[i][j] = zero4;

    for (int step = 0; step < 36; ++step) {
        const int rs = step >> 2, ch = step & 3;
        const int dr = rs / 3 - 1, dc = rs % 3 - 1;
        const int aoff = (dr * WP + dc) * C_IN + ch * 32;        // wave-uniform
        const size_t boff = (size_t)(((rs * 4 + ch) * 2 + nt) * 4096) + bbase;

        __syncthreads();   // prior iteration's frag reads complete
        gld16(gA0 + aoff, (void*)(As + tid * 8));
        gld16(gA1 + aoff, (void*)(As + 2048 + tid * 8));
        gld16(wt + boff,        (void*)(Bs + tid * 8));
        gld16(wt + boff + 2048, (void*)(Bs + 2048 + tid * 8));
        __syncthreads();   // staging visible

        bfvec8 af[4], bf[4];
        #pragma unroll
        for (int mi = 0; mi < 4; ++mi)
            af[mi] = *(const bfvec8*)&As[(wrow + mi * 16 + r16) * 32 + qsw];
        #pragma unroll
        for (int ni = 0; ni < 4; ++ni)
            bf[ni] = *(const bfvec8*)&Bs[(wcol + ni * 16 + r16) * 32 + qsw];

        #pragma unroll
        for (int mi = 0; mi < 4; ++mi)
            #pragma unroll
            for (int ni = 0; ni < 4; ++ni)
                acc[mi][ni] = __builtin_amdgcn_mfma_f32_16x16x32_bf16(
                    af[mi], bf[ni], acc[mi][ni], 0, 0, 0);
    }

    // epilogue: D col=lane&15 -> k, row=quad*4+i -> m; i is m-consecutive ->
    // hwe-consecutive (3136%4==0, base%4==0) -> dwordx4 stores
    const int ntile = nt * 128;
    #pragma unroll
    for (int ni = 0; ni < 4; ++ni) {
        const int k = ntile + wcol + ni * 16 + r16;
        const float bb = bias[k];
        #pragma unroll
        for (int mi = 0; mi < 4; ++mi) {
            const int mb  = mtile + wrow + mi * 16 + quad * 4;
            const int ne  = mb / HW;
            const int hwe = mb - ne * HW;
            f32x4 v;
            #pragma unroll
            for (int i = 0; i < 4; ++i) v[i] = acc[mi][ni][i] + bb;
            *(f32x4*)(out + ((size_t)ne * K_OUT + k) * HW + hwe) = v;
        }
    }
}

extern "C" void kernel_launch(void* const* d_in, const int* in_sizes, int n_in,
                              void* d_out, int out_size, void* d_ws, size_t ws_size,
                              hipStream_t stream) {
    const float* x    = (const float*)d_in[0];
    const float* wgt  = (const float*)d_in[1];
    const float* bias = (const float*)d_in[2];
    float* out = (float*)d_out;

    unsigned short* xp = (unsigned short*)d_ws;
    unsigned short* wt = (unsigned short*)((char*)d_ws + XP_BYTES);

    hipMemsetAsync(d_ws, 0, XP_BYTES, stream);                       // halo zeros
    xpose<<<dim3(N_IMG * Hd), dim3(256), 0, stream>>>(x, xp);
    wxform<<<dim3((int)(WT_ELEMS / 256)), dim3(256), 0, stream>>>(wgt, wt);
    conv_gemm<<<dim3(1568), dim3(256), 0, stream>>>(xp, wt, bias, out);
}